// Round 8
// baseline (2760.211 us; speedup 1.0000x reference)
//
#include <hip/hip_runtime.h>
#include <hip/hip_bf16.h>

#define NB 128
#define LSEQ 512
#define HD 512
#define NI (NB * LSEQ)
#define MAX_DEPTH 40

typedef __attribute__((ext_vector_type(8))) short bf16x8;
typedef __attribute__((ext_vector_type(4))) float f32x4;
typedef __attribute__((ext_vector_type(2))) float f32x2;
typedef __attribute__((ext_vector_type(4))) unsigned int u32x4;
typedef __attribute__((ext_vector_type(2))) unsigned short u16x2;

static __device__ __forceinline__ unsigned f2b(float x) {
    union { __hip_bfloat16 b; unsigned short u; } cv;
    cv.b = __float2bfloat16(x);
    return (unsigned)cv.u;
}
static __device__ __forceinline__ float b2f(unsigned short u) {
    union { __hip_bfloat16 b; unsigned short u; } cv;
    cv.u = u;
    return __bfloat162float(cv.b);
}

// ---------------------------------------------------------------------------
// setup: h0 -> bf16, zero page
// ---------------------------------------------------------------------------
__global__ __launch_bounds__(256) void setup_kernel(
    const float* __restrict__ h0,
    unsigned short* __restrict__ h0bf, unsigned short* __restrict__ zeropage)
{
    int i = blockIdx.x * 256 + threadIdx.x;
    if (i < NB * HD) h0bf[i] = (unsigned short)f2b(h0[i]);
    if (i < 1024) zeropage[i] = 0;
}

// ---------------------------------------------------------------------------
// pack: W [1536][512] row-major -> MFMA-B-frag-major bf16.
// lane l of frag (ct,kc) holds B[k=kc*32+(l>>4)*8+j][col=ct*16+(l&15)], j=0..7
// element index: ((ct*16+kc)*64 + lane)*8 + j ; ct = global col/16 (0..95)
// ---------------------------------------------------------------------------
__global__ __launch_bounds__(256) void pack_kernel(
    const float* __restrict__ W_ih, const float* __restrict__ W_hh,
    unsigned short* __restrict__ Xpack, unsigned short* __restrict__ Hpack)
{
    int idx = blockIdx.x * 256 + threadIdx.x;   // = g*512 + k
    if (idx >= 1536 * 512) return;
    int g = idx >> 9, k = idx & 511;
    int ct = g >> 4, lane_lo = g & 15;
    int kc = k >> 5, kin = k & 31;
    int lane = (kin >> 3) * 16 + lane_lo;
    int j = kin & 7;
    int p = ((ct * 16 + kc) * 64 + lane) * 8 + j;
    Xpack[p] = (unsigned short)f2b(W_ih[idx]);
    Hpack[p] = (unsigned short)f2b(W_hh[idx]);
}

// ---------------------------------------------------------------------------
// sched: bucket (n,l) by depth-within-episode; emit permutation arrays:
//   items[pos] = (n<<16)|l ; pos_of[n*L+l] = pos ;
//   prevref[pos] = prev hperm row (>=0) | -1 (zero h) | -(n+2) (h0 row n)
// ---------------------------------------------------------------------------
__global__ __launch_bounds__(128) void sched_kernel(
    const int* __restrict__ is_init,
    int* __restrict__ counts_g, int* __restrict__ offsets_g,
    unsigned* __restrict__ items_g, int* __restrict__ pos_of,
    int* __restrict__ prevref)
{
    __shared__ int cnt[LSEQ];
    __shared__ int off[LSEQ];
    int tid = threadIdx.x;
    for (int i = tid; i < LSEQ; i += 128) cnt[i] = 0;
    __syncthreads();
    {
        int d = 0;
        for (int l = 0; l < LSEQ; l++) {
            int ii = is_init[tid * LSEQ + l];
            d = ii ? 0 : (l == 0 ? 0 : d + 1);
            atomicAdd(&cnt[d], 1);
        }
    }
    __syncthreads();
    if (tid == 0) {
        int acc = 0;
        for (int i = 0; i < LSEQ; i++) { off[i] = acc; acc += cnt[i]; }
    }
    __syncthreads();
    for (int i = tid; i < LSEQ; i += 128) {
        counts_g[i] = cnt[i];
        offsets_g[i] = off[i];
        cnt[i] = 0;
    }
    __syncthreads();
    {
        int d = 0;
        int prevpos = 0;
        for (int l = 0; l < LSEQ; l++) {
            int ii = is_init[tid * LSEQ + l];
            d = ii ? 0 : (l == 0 ? 0 : d + 1);
            int pos = off[d] + atomicAdd(&cnt[d], 1);
            items_g[pos] = (unsigned)((tid << 16) | l);
            pos_of[tid * LSEQ + l] = pos;
            int pr;
            if (d == 0) pr = ii ? -1 : -(tid + 2);
            else pr = prevpos;
            prevref[pos] = pr;
            prevpos = pos;
        }
    }
}

// ---------------------------------------------------------------------------
// gxp: gx[pos][0:1536] = x[item(pos)] @ W_ih^T + b_ih (all 3 gates), bf16.
// Block = 32 positions x 768 cols (blockIdx.y = col half), 8 waves:
// wave w owns 96 cols (6 ct-frags); acc[2][6] = 48 f32x4 regs.
// NT on x reads and gate writes (streaming; keep Xpack L2-resident).
// ---------------------------------------------------------------------------
__global__ __launch_bounds__(512, 2) void gxp_kernel(
    const float* __restrict__ inp, const unsigned short* __restrict__ Xpack,
    const float* __restrict__ b_ih, const unsigned* __restrict__ items,
    unsigned short* __restrict__ gxp)
{
    const int tile = blockIdx.x;              // 2048 tiles of 32 positions
    const int y = blockIdx.y;                 // col half (768 cols)
    const int tid = threadIdx.x;
    const int w = tid >> 6, lane = tid & 63;
    const int l15 = lane & 15, lhi = lane >> 4;

    __shared__ unsigned short As[32 * 512];   // 32 KB, XOR-swizzled

    // stage 32 rows x 512 K (fp32 -> bf16), gathered via items
    {
        int r = tid >> 4, kb = (tid & 15) * 32;
        unsigned wv = items[tile * 32 + r];
        int n = (int)(wv >> 16), l = (int)(wv & 0xffff);
        const float* src = inp + ((size_t)(n * LSEQ + l)) * HD + kb;
        #pragma unroll
        for (int i = 0; i < 4; ++i) {
            f32x4 v0 = __builtin_nontemporal_load((const f32x4*)(src + i * 8));
            f32x4 v1 = __builtin_nontemporal_load((const f32x4*)(src + i * 8 + 4));
            u32x4 u;
            u[0] = f2b(v0[0]) | (f2b(v0[1]) << 16);
            u[1] = f2b(v0[2]) | (f2b(v0[3]) << 16);
            u[2] = f2b(v1[0]) | (f2b(v1[1]) << 16);
            u[3] = f2b(v1[2]) | (f2b(v1[3]) << 16);
            int byte = (r * 1024 + (kb + i * 8) * 2) ^ ((r & 7) << 4);
            *(u32x4*)((char*)As + byte) = u;
        }
    }
    __syncthreads();

    const int ctg0 = y * 48 + w * 6;          // global ct base for this wave
    f32x4 acc[2][6];
    #pragma unroll
    for (int ct = 0; ct < 6; ++ct) {
        float b = b_ih[(ctg0 + ct) * 16 + l15];
        acc[0][ct] = (f32x4){b, b, b, b};
        acc[1][ct] = (f32x4){b, b, b, b};
    }
    const unsigned short* xpk = Xpack + lane * 8;

    #pragma unroll
    for (int kc = 0; kc < 16; ++kc) {
        bf16x8 a[2];
        #pragma unroll
        for (int mf = 0; mf < 2; ++mf) {
            int r = mf * 16 + l15;
            int byte = (r * 1024 + (kc * 32 + lhi * 8) * 2) ^ ((r & 7) << 4);
            a[mf] = *(const bf16x8*)((const char*)As + byte);
        }
        #pragma unroll
        for (int ct = 0; ct < 6; ++ct) {
            bf16x8 bv = *(const bf16x8*)(xpk + (size_t)((ctg0 + ct) * 16 + kc) * 512);
            acc[0][ct] = __builtin_amdgcn_mfma_f32_16x16x32_bf16(a[0], bv, acc[0][ct], 0, 0, 0);
            acc[1][ct] = __builtin_amdgcn_mfma_f32_16x16x32_bf16(a[1], bv, acc[1][ct], 0, 0, 0);
        }
    }

    // write: gxp[pos][col], contiguous rows (C/D: row=(l>>4)*4+v, col=l&15)
    #pragma unroll
    for (int mf = 0; mf < 2; ++mf)
    #pragma unroll
    for (int v = 0; v < 4; ++v) {
        size_t p = (size_t)(tile * 32 + mf * 16 + lhi * 4 + v);
        #pragma unroll
        for (int ct = 0; ct < 6; ++ct) {
            int col = (ctg0 + ct) * 16 + l15;
            __builtin_nontemporal_store((unsigned short)f2b(acc[mf][ct][v]),
                                        gxp + p * 1536 + col);
        }
    }
}

// ---------------------------------------------------------------------------
// phase: H-side GEMM + fused GRU epilogue over contiguous positions
// [off[d], off[d]+count). Block = 64 positions x 256 cols/gate
// (blockIdx.y = col half); wave w owns 32 cols/gate -> acc 24 f32x4.
// K-chunks ordered so the LAST staged chunk is this block's y-half: the
// epilogue reads hprev from LDS (no global re-read). Streaming reads are NT
// so the Hpack B-frags stay L2-resident. ref==-1 rows skip loads (zeros).
// ---------------------------------------------------------------------------
__global__ __launch_bounds__(512, 2) void phase_kernel(
    int d,
    const unsigned short* __restrict__ Hpack, const float* __restrict__ b_hh,
    const int* __restrict__ counts, const int* __restrict__ offsets,
    const int* __restrict__ prevref,
    const unsigned short* __restrict__ gxp,
    const unsigned short* __restrict__ h0bf,
    unsigned short* __restrict__ hperm)
{
    const int count = counts[d];
    if (count == 0) return;
    const int base = offsets[d];
    const int y = blockIdx.y;
    const int tid = threadIdx.x;
    const int w = tid >> 6, lane = tid & 63;
    const int l15 = lane & 15, lhi = lane >> 4;

    __shared__ unsigned short As[64 * 256];   // 32 KB

    float bR[2], bZ[2], bN[2];
    #pragma unroll
    for (int cf = 0; cf < 2; ++cf) {
        int colg = y * 256 + w * 32 + cf * 16 + l15;
        bR[cf] = b_hh[colg];
        bZ[cf] = b_hh[512 + colg];
        bN[cf] = b_hh[1024 + colg];
    }
    const unsigned short* hpk = Hpack + lane * 8;

    const int ntiles = (count + 63) >> 6;
    for (int tile = blockIdx.x; tile < ntiles; tile += gridDim.x) {
        f32x4 aR[4][2], aZ[4][2], aN[4][2];
        #pragma unroll
        for (int mf = 0; mf < 4; ++mf)
        #pragma unroll
        for (int cf = 0; cf < 2; ++cf) {
            aR[mf][cf] = (f32x4){bR[cf], bR[cf], bR[cf], bR[cf]};
            aZ[mf][cf] = (f32x4){bZ[cf], bZ[cf], bZ[cf], bZ[cf]};
            aN[mf][cf] = (f32x4){bN[cf], bN[cf], bN[cf], bN[cf]};
        }

        #pragma unroll
        for (int cc = 0; cc < 2; ++cc) {
            const int ch = cc ? y : (1 - y);   // last staged chunk = y's cols
            __syncthreads();    // prev chunk's readers (incl. epilogue) done
            {
                int r = tid >> 3, kb = (tid & 7) * 32;
                int g = tile * 64 + r;
                u32x4 u[4];
                #pragma unroll
                for (int i = 0; i < 4; ++i) u[i] = (u32x4){0, 0, 0, 0};
                if (g < count) {
                    int ref = prevref[base + g];
                    if (ref >= 0) {
                        const unsigned short* src = hperm + (size_t)ref * HD + ch * 256 + kb;
                        #pragma unroll
                        for (int i = 0; i < 4; ++i)
                            u[i] = __builtin_nontemporal_load((const u32x4*)(src + i * 8));
                    } else if (ref != -1) {
                        const unsigned short* src = h0bf + (size_t)(-ref - 2) * HD + ch * 256 + kb;
                        #pragma unroll
                        for (int i = 0; i < 4; ++i)
                            u[i] = *(const u32x4*)(src + i * 8);
                    }
                    // ref == -1: zeros (episode reset), no load at all
                }
                #pragma unroll
                for (int i = 0; i < 4; ++i) {
                    int byte = (r * 512 + (kb + i * 8) * 2) ^ ((r & 7) << 4);
                    *(u32x4*)((char*)As + byte) = u[i];
                }
            }
            __syncthreads();
            #pragma unroll
            for (int kcl = 0; kcl < 8; ++kcl) {
                const int kcg = ch * 8 + kcl;
                bf16x8 a[4];
                #pragma unroll
                for (int mf = 0; mf < 4; ++mf) {
                    int r = mf * 16 + l15;
                    int byte = (r * 512 + (kcl * 32 + lhi * 8) * 2) ^ ((r & 7) << 4);
                    a[mf] = *(const bf16x8*)((const char*)As + byte);
                }
                #pragma unroll
                for (int cf = 0; cf < 2; ++cf) {
                    const int ctb = y * 16 + w * 2 + cf;   // within-gate ct (0..31)
                    bf16x8 vR = *(const bf16x8*)(hpk + (size_t)(ctb * 16 + kcg) * 512);
                    bf16x8 vZ = *(const bf16x8*)(hpk + (size_t)((32 + ctb) * 16 + kcg) * 512);
                    bf16x8 vN = *(const bf16x8*)(hpk + (size_t)((64 + ctb) * 16 + kcg) * 512);
                    #pragma unroll
                    for (int mf = 0; mf < 4; ++mf) {
                        aR[mf][cf] = __builtin_amdgcn_mfma_f32_16x16x32_bf16(a[mf], vR, aR[mf][cf], 0, 0, 0);
                        aZ[mf][cf] = __builtin_amdgcn_mfma_f32_16x16x32_bf16(a[mf], vZ, aZ[mf][cf], 0, 0, 0);
                        aN[mf][cf] = __builtin_amdgcn_mfma_f32_16x16x32_bf16(a[mf], vN, aN[mf][cf], 0, 0, 0);
                    }
                }
            }
        }

        // epilogue: GRU pointwise; hprev read from the LDS tile (y's chunk),
        // gxp rows streamed NT, hperm store normal (next phase re-reads it).
        #pragma unroll
        for (int mf = 0; mf < 4; ++mf)
        #pragma unroll
        for (int v = 0; v < 4; ++v) {
            int rloc = mf * 16 + lhi * 4 + v;
            int g = tile * 64 + rloc;
            if (g >= count) continue;
            size_t p = (size_t)(base + g);
            #pragma unroll
            for (int cf = 0; cf < 2; ++cf) {
                int c_loc = w * 32 + cf * 16 + l15;
                int lbyte = (rloc * 512 + c_loc * 2) ^ ((rloc & 7) << 4);
                float hp = b2f(*(const unsigned short*)((const char*)As + lbyte));
                int colg = y * 256 + c_loc;
                const unsigned short* gp = gxp + p * 1536 + colg;
                float gr = b2f(__builtin_nontemporal_load(gp));
                float gz = b2f(__builtin_nontemporal_load(gp + 512));
                float gn = b2f(__builtin_nontemporal_load(gp + 1024));
                float r = 1.f / (1.f + __expf(-(gr + aR[mf][cf][v])));
                float z = 1.f / (1.f + __expf(-(gz + aZ[mf][cf][v])));
                float nn = tanhf(gn + r * aN[mf][cf][v]);
                hperm[p * HD + colg] = (unsigned short)f2b((1.f - z) * nn + z * hp);
            }
        }
    }
}

// ---------------------------------------------------------------------------
// hlast: h[n, L-1, :] -> fp32 ws (via pos_of; before hexp overwrites hperm)
// ---------------------------------------------------------------------------
__global__ __launch_bounds__(256) void hlast_kernel(
    const unsigned short* __restrict__ hperm, const int* __restrict__ pos_of,
    float* __restrict__ hlast)
{
    int i = blockIdx.x * 256 + threadIdx.x;
    if (i >= NB * HD) return;
    int n = i >> 9, c = i & 511;
    size_t pos = (size_t)pos_of[n * LSEQ + (LSEQ - 1)];
    hlast[i] = b2f(hperm[pos * HD + c]);
}

// ---------------------------------------------------------------------------
// LayerNorm: out1[n,l] = LN(hperm[pos_of[n,l]] + inp[n,l]) * gamma + beta
// ---------------------------------------------------------------------------
__global__ __launch_bounds__(256) void ln_kernel(
    const unsigned short* __restrict__ hperm, const int* __restrict__ pos_of,
    const float* __restrict__ inp,
    const float* __restrict__ gamma, const float* __restrict__ beta,
    float* __restrict__ out1)
{
    size_t row = blockIdx.x;
    int tid = threadIdx.x;
    int c = tid * 2;
    size_t pos = (size_t)pos_of[row];
    const unsigned short* yrow = hperm + pos * HD;
    const float* xrow = inp + row * HD;
    u16x2 yv = __builtin_nontemporal_load((const u16x2*)(yrow + c));
    f32x2 xv = __builtin_nontemporal_load((const f32x2*)(xrow + c));
    float a = b2f(yv[0]) + xv[0];
    float b = b2f(yv[1]) + xv[1];
    float s = a + b, ss = a * a + b * b;
    #pragma unroll
    for (int m = 1; m < 64; m <<= 1) {
        s  += __shfl_xor(s, m, 64);
        ss += __shfl_xor(ss, m, 64);
    }
    __shared__ float ps[4], pss[4];
    int w = tid >> 6;
    if ((tid & 63) == 0) { ps[w] = s; pss[w] = ss; }
    __syncthreads();
    s  = ps[0] + ps[1] + ps[2] + ps[3];
    ss = pss[0] + pss[1] + pss[2] + pss[3];
    float mu = s * (1.f / 512.f);
    float var = ss * (1.f / 512.f) - mu * mu;
    float inv = rsqrtf(var + 1e-5f);
    float2 gv = *(const float2*)(gamma + c);
    float2 bv = *(const float2*)(beta + c);
    f32x2 o;
    o[0] = (a - mu) * inv * gv.x + bv.x;
    o[1] = (b - mu) * inv * gv.y + bv.y;
    __builtin_nontemporal_store(o, (f32x2*)(out1 + row * HD + c));
}

// ---------------------------------------------------------------------------
// hexp: out2[n,l,:] = hlast[n,:]  (overwrites gxp tail + hperm; runs last)
// ---------------------------------------------------------------------------
__global__ __launch_bounds__(256) void hexp_kernel(
    const float* __restrict__ hlast, float* __restrict__ out2)
{
    size_t idx = (size_t)blockIdx.x * 256 + threadIdx.x;   // float4 units
    if (idx >= (size_t)NI * HD / 4) return;
    int per_n = LSEQ * HD / 4;
    int n = (int)(idx / per_n);
    int c4 = (int)(idx & (HD / 4 - 1));
    f32x4 v = *(const f32x4*)(hlast + n * HD + c4 * 4);   // 256 KB, reused: cached
    __builtin_nontemporal_store(v, (f32x4*)(out2 + idx * 4));
}

// ---------------------------------------------------------------------------
extern "C" void kernel_launch(void* const* d_in, const int* in_sizes, int n_in,
                              void* d_out, int out_size, void* d_ws, size_t ws_size,
                              hipStream_t stream)
{
    const float* inp   = (const float*)d_in[0];
    const float* h0    = (const float*)d_in[1];
    const int*  is_ini = (const int*)d_in[2];
    const float* W_ih  = (const float*)d_in[3];
    const float* W_hh  = (const float*)d_in[4];
    const float* b_ih  = (const float*)d_in[5];
    const float* b_hh  = (const float*)d_in[6];
    const float* gamma = (const float*)d_in[7];
    const float* beta  = (const float*)d_in[8];

    const size_t NLH = (size_t)NI * HD;            // 33,554,432
    float* out1 = (float*)d_out;
    float* out2 = out1 + NLH;
    // d_out overlay (268.4 MB):
    //   gxp   bf16 [NI][1536] = 201.3 MB at offset 0      (dead after phases)
    //   hperm bf16 [NI][512]  =  67.1 MB at offset 201.3  (dead after hlast/ln)
    unsigned short* gxp   = (unsigned short*)d_out;
    unsigned short* hperm = gxp + (size_t)NI * 1536;

    unsigned short* Xpack = (unsigned short*)d_ws;            // 1.5 MB
    unsigned short* Hpack = Xpack + 1536 * 512;               // 1.5 MB
    int* counts  = (int*)(Hpack + 1536 * 512);                // 2 KB
    int* offsets = counts + LSEQ;                             // 2 KB
    unsigned* items = (unsigned*)(offsets + LSEQ);            // 256 KB
    int* pos_of  = (int*)(items + NI);                        // 256 KB
    int* prevref = pos_of + NI;                               // 256 KB
    unsigned short* h0bf = (unsigned short*)(prevref + NI);   // 128 KB
    unsigned short* zeropage = h0bf + NB * HD;                // 2 KB
    float* hlast = (float*)(zeropage + 1024);                 // 256 KB

    setup_kernel<<<(NB * HD + 255) / 256, 256, 0, stream>>>(h0, h0bf, zeropage);
    pack_kernel<<<(1536 * 512 + 255) / 256, 256, 0, stream>>>(W_ih, W_hh, Xpack, Hpack);
    sched_kernel<<<1, 128, 0, stream>>>(is_ini, counts, offsets, items, pos_of, prevref);

    gxp_kernel<<<dim3(NI / 32, 2), 512, 0, stream>>>(inp, Xpack, b_ih, items, gxp);

    for (int d = 0; d < MAX_DEPTH; d++) {
        int gx = 512 >> d;
        if (gx < 2) gx = 2;
        phase_kernel<<<dim3(gx, 2), 512, 0, stream>>>(
            d, Hpack, b_hh, counts, offsets, prevref,
            gxp, h0bf, hperm);
    }

    hlast_kernel<<<(NB * HD + 255) / 256, 256, 0, stream>>>(hperm, pos_of, hlast);
    ln_kernel<<<NI, 256, 0, stream>>>(hperm, pos_of, inp, gamma, beta, out1);
    hexp_kernel<<<(int)(NLH / 4 / 256), 256, 0, stream>>>(hlast, out2);
}

// Round 9
// 1017.507 us; speedup vs baseline: 2.7127x; 2.7127x over previous
//
#include <hip/hip_runtime.h>
#include <hip/hip_bf16.h>

#define NB 128
#define LSEQ 512
#define HD 512
#define NI (NB * LSEQ)
#define MAX_DEPTH 40
#define SLICES 32
#define GRPS 16
#define MTILE 256

typedef __attribute__((ext_vector_type(8))) short bf16x8;
typedef __attribute__((ext_vector_type(4))) float f32x4;

static __device__ __forceinline__ unsigned f2b(float x) {
    union { __hip_bfloat16 b; unsigned short u; } cv;
    cv.b = __float2bfloat16(x);
    return (unsigned)cv.u;
}
static __device__ __forceinline__ float b2f(unsigned short u) {
    union { __hip_bfloat16 b; unsigned short u; } cv;
    cv.u = u;
    return __bfloat162float(cv.b);
}

// ---------------------------------------------------------------------------
// setup: h0 -> bf16, zero page (>=1024 elems: A-loads read up to 544)
// ---------------------------------------------------------------------------
__global__ __launch_bounds__(256) void setup_kernel(
    const float* __restrict__ h0,
    unsigned short* __restrict__ h0bf, unsigned short* __restrict__ zeropage)
{
    int i = blockIdx.x * 256 + threadIdx.x;
    if (i < NB * HD) h0bf[i] = (unsigned short)f2b(h0[i]);
    if (i < 1024) zeropage[i] = 0;
}

// ---------------------------------------------------------------------------
// pack: W [1536][512] row-major -> MFMA-B-frag-major bf16.
// lane l of frag (ct,kc) holds B[k=kc*32+(l>>4)*8+j][col=ct*16+(l&15)], j=0..7
// element index: ((ct*16+kc)*64 + lane)*8 + j ; ct = global col/16 (0..95)
// ---------------------------------------------------------------------------
__global__ __launch_bounds__(256) void pack_kernel(
    const float* __restrict__ W_ih, const float* __restrict__ W_hh,
    unsigned short* __restrict__ Xpack, unsigned short* __restrict__ Hpack)
{
    int idx = blockIdx.x * 256 + threadIdx.x;   // = g*512 + k
    if (idx >= 1536 * 512) return;
    int g = idx >> 9, k = idx & 511;
    int ct = g >> 4, lane_lo = g & 15;
    int kc = k >> 5, kin = k & 31;
    int lane = (kin >> 3) * 16 + lane_lo;
    int j = kin & 7;
    int p = ((ct * 16 + kc) * 64 + lane) * 8 + j;
    Xpack[p] = (unsigned short)f2b(W_ih[idx]);
    Hpack[p] = (unsigned short)f2b(W_hh[idx]);
}

// ---------------------------------------------------------------------------
// sched: bucket (n,l) by depth-within-episode; emit permutation arrays:
//   items[pos] = (n<<16)|l ; pos_of[n*L+l] = pos ;
//   prevoff[pos] = hperm elem offset (>=0) | -1 (zero h) | -(n*512+2) (h0)
// ---------------------------------------------------------------------------
__global__ __launch_bounds__(128) void sched_kernel(
    const int* __restrict__ is_init,
    int* __restrict__ counts_g, int* __restrict__ offsets_g,
    unsigned* __restrict__ items_g, int* __restrict__ pos_of,
    int* __restrict__ prevoff)
{
    __shared__ int cnt[LSEQ];
    __shared__ int off[LSEQ];
    int tid = threadIdx.x;
    for (int i = tid; i < LSEQ; i += 128) cnt[i] = 0;
    __syncthreads();
    {
        int d = 0;
        for (int l = 0; l < LSEQ; l++) {
            int ii = is_init[tid * LSEQ + l];
            d = ii ? 0 : (l == 0 ? 0 : d + 1);
            atomicAdd(&cnt[d], 1);
        }
    }
    __syncthreads();
    if (tid == 0) {
        int acc = 0;
        for (int i = 0; i < LSEQ; i++) { off[i] = acc; acc += cnt[i]; }
    }
    __syncthreads();
    for (int i = tid; i < LSEQ; i += 128) {
        counts_g[i] = cnt[i];
        offsets_g[i] = off[i];
        cnt[i] = 0;
    }
    __syncthreads();
    {
        int d = 0;
        int prevpos = 0;
        for (int l = 0; l < LSEQ; l++) {
            int ii = is_init[tid * LSEQ + l];
            d = ii ? 0 : (l == 0 ? 0 : d + 1);
            int pos = off[d] + atomicAdd(&cnt[d], 1);
            items_g[pos] = (unsigned)((tid << 16) | l);
            pos_of[tid * LSEQ + l] = pos;
            int pr;
            if (d == 0) pr = ii ? -1 : -(tid * 512 + 2);
            else pr = prevpos * 512;
            prevoff[pos] = pr;
            prevpos = pos;
        }
    }
}

// ---------------------------------------------------------------------------
// gxp: gx[pos][0:1536] = x[item(pos)] @ W_ih^T + b_ih (all 3 gates), bf16.
// Block = 32 positions x 768 cols (blockIdx.y = col half), 8 waves.
// ---------------------------------------------------------------------------
__global__ __launch_bounds__(512, 2) void gxp_kernel(
    const float* __restrict__ inp, const unsigned short* __restrict__ Xpack,
    const float* __restrict__ b_ih, const unsigned* __restrict__ items,
    unsigned short* __restrict__ gxp)
{
    const int tile = blockIdx.x;              // 2048 tiles of 32 positions
    const int y = blockIdx.y;                 // col half (768 cols)
    const int tid = threadIdx.x;
    const int w = tid >> 6, lane = tid & 63;
    const int l15 = lane & 15, lhi = lane >> 4;

    __shared__ unsigned short As[32 * 512];   // 32 KB, XOR-swizzled

    {
        int r = tid >> 4, kb = (tid & 15) * 32;
        unsigned wv = items[tile * 32 + r];
        int n = (int)(wv >> 16), l = (int)(wv & 0xffff);
        const float* src = inp + ((size_t)(n * LSEQ + l)) * HD + kb;
        #pragma unroll
        for (int i = 0; i < 4; ++i) {
            float4 v0 = *(const float4*)(src + i * 8);
            float4 v1 = *(const float4*)(src + i * 8 + 4);
            uint4 u;
            u.x = f2b(v0.x) | (f2b(v0.y) << 16);
            u.y = f2b(v0.z) | (f2b(v0.w) << 16);
            u.z = f2b(v1.x) | (f2b(v1.y) << 16);
            u.w = f2b(v1.z) | (f2b(v1.w) << 16);
            int byte = (r * 1024 + (kb + i * 8) * 2) ^ ((r & 7) << 4);
            *(uint4*)((char*)As + byte) = u;
        }
    }
    __syncthreads();

    const int ctg0 = y * 48 + w * 6;          // global ct base for this wave
    f32x4 acc[2][6];
    #pragma unroll
    for (int ct = 0; ct < 6; ++ct) {
        float b = b_ih[(ctg0 + ct) * 16 + l15];
        acc[0][ct] = (f32x4){b, b, b, b};
        acc[1][ct] = (f32x4){b, b, b, b};
    }
    const unsigned short* xpk = Xpack + lane * 8;

    #pragma unroll
    for (int kc = 0; kc < 16; ++kc) {
        bf16x8 a[2];
        #pragma unroll
        for (int mf = 0; mf < 2; ++mf) {
            int r = mf * 16 + l15;
            int byte = (r * 1024 + (kc * 32 + lhi * 8) * 2) ^ ((r & 7) << 4);
            a[mf] = *(const bf16x8*)((const char*)As + byte);
        }
        #pragma unroll
        for (int ct = 0; ct < 6; ++ct) {
            bf16x8 bv = *(const bf16x8*)(xpk + (size_t)((ctg0 + ct) * 16 + kc) * 512);
            acc[0][ct] = __builtin_amdgcn_mfma_f32_16x16x32_bf16(a[0], bv, acc[0][ct], 0, 0, 0);
            acc[1][ct] = __builtin_amdgcn_mfma_f32_16x16x32_bf16(a[1], bv, acc[1][ct], 0, 0, 0);
        }
    }

    #pragma unroll
    for (int mf = 0; mf < 2; ++mf)
    #pragma unroll
    for (int v = 0; v < 4; ++v) {
        size_t p = (size_t)(tile * 32 + mf * 16 + lhi * 4 + v);
        #pragma unroll
        for (int ct = 0; ct < 6; ++ct) {
            int col = (ctg0 + ct) * 16 + l15;
            gxp[p * 1536 + col] = (unsigned short)f2b(acc[mf][ct][v]);
        }
    }
}

// ---------------------------------------------------------------------------
// wphase: depth-d GRU step with LDS-RESIDENT weight slice.
// Grid: 512 blocks, bid = slice*16 + grp  (slice 0..31, grp 0..15).
//   -> bid%8 = grp%8: all 32 slices of a group land on the same XCD, so the
//      32x re-read of hprev/gxp rows is L2-shared, not HBM-amplified.
// Block: 512 thr (8 waves). LDS = 48 KB: 3 gates x 1 ct (16 out-cols) x K=512
// B-frags, loaded ONCE per launch. Item tiles of 256 stream through:
// A-frags read DIRECTLY from global (16 rows x 64 B full lines per kstep),
// wave w owns item-frags {2w, 2w+1}; 6 MFMA : 3 ds_read : 2 global per kstep.
// Blocks with grp >= ntiles exit before the weight load (cheap tail).
// ---------------------------------------------------------------------------
__global__ __launch_bounds__(512, 4) void wphase_kernel(
    int d,
    const unsigned short* __restrict__ Hpack, const float* __restrict__ b_hh,
    const int* __restrict__ counts, const int* __restrict__ offsets,
    const int* __restrict__ prevoff,
    const unsigned short* __restrict__ gxp,
    const unsigned short* __restrict__ h0bf, const unsigned short* __restrict__ zeropage,
    unsigned short* __restrict__ hperm)
{
    const int count = counts[d];
    const int slice = blockIdx.x >> 4;
    const int grp = blockIdx.x & 15;
    const int ntiles = (count + MTILE - 1) / MTILE;
    if (grp >= ntiles) return;            // count==0 or small: exit pre-LDS
    const int base = offsets[d];
    const int tid = threadIdx.x;
    const int w = tid >> 6, lane = tid & 63;
    const int l15 = lane & 15, lhi = lane >> 4;

    __shared__ unsigned short Wl[3 * 16 * 512];   // 48 KB

    // load weight slice: gate g -> global ct = g*32 + slice (16 KB each)
    #pragma unroll
    for (int i = 0; i < 6; ++i) {
        int q = tid + i * 512;            // uint4 index, 3072 total
        int g = q >> 10, rem = q & 1023;
        ((uint4*)Wl)[q] = *((const uint4*)(Hpack + (size_t)(g * 32 + slice) * 8192) + rem);
    }

    float bias[3];
    #pragma unroll
    for (int g = 0; g < 3; ++g)
        bias[g] = b_hh[g * 512 + slice * 16 + l15];

    __syncthreads();

    for (int tile = grp; tile < ntiles; tile += GRPS) {
        // per-lane A-row pointers for item-frags 2w, 2w+1 (row = ... + l&15)
        const unsigned short* rp0;
        const unsigned short* rp1;
        {
            int row0 = tile * MTILE + (2 * w) * 16 + l15;
            int row1 = row0 + 16;
            rp0 = zeropage; rp1 = zeropage;
            if (row0 < count) {
                int off = prevoff[base + row0];
                rp0 = (off >= 0) ? (hperm + off)
                     : (off == -1 ? zeropage : (h0bf + (-off - 2)));
            }
            if (row1 < count) {
                int off = prevoff[base + row1];
                rp1 = (off >= 0) ? (hperm + off)
                     : (off == -1 ? zeropage : (h0bf + (-off - 2)));
            }
        }

        f32x4 aR0 = (f32x4){bias[0], bias[0], bias[0], bias[0]}, aR1 = aR0;
        f32x4 aZ0 = (f32x4){bias[1], bias[1], bias[1], bias[1]}, aZ1 = aZ0;
        f32x4 aN0 = (f32x4){bias[2], bias[2], bias[2], bias[2]}, aN1 = aN0;

        #pragma unroll 4
        for (int ks = 0; ks < 16; ++ks) {
            bf16x8 a0 = *(const bf16x8*)(rp0 + lhi * 8 + ks * 32);
            bf16x8 a1 = *(const bf16x8*)(rp1 + lhi * 8 + ks * 32);
            bf16x8 bR = *(const bf16x8*)(Wl + (0 * 16 + ks) * 512 + lane * 8);
            bf16x8 bZ = *(const bf16x8*)(Wl + (1 * 16 + ks) * 512 + lane * 8);
            bf16x8 bN = *(const bf16x8*)(Wl + (2 * 16 + ks) * 512 + lane * 8);
            aR0 = __builtin_amdgcn_mfma_f32_16x16x32_bf16(a0, bR, aR0, 0, 0, 0);
            aR1 = __builtin_amdgcn_mfma_f32_16x16x32_bf16(a1, bR, aR1, 0, 0, 0);
            aZ0 = __builtin_amdgcn_mfma_f32_16x16x32_bf16(a0, bZ, aZ0, 0, 0, 0);
            aZ1 = __builtin_amdgcn_mfma_f32_16x16x32_bf16(a1, bZ, aZ1, 0, 0, 0);
            aN0 = __builtin_amdgcn_mfma_f32_16x16x32_bf16(a0, bN, aN0, 0, 0, 0);
            aN1 = __builtin_amdgcn_mfma_f32_16x16x32_bf16(a1, bN, aN1, 0, 0, 0);
        }

        // epilogue: GRU pointwise (C/D: item=(l>>4)*4+v, col=l&15)
        #pragma unroll
        for (int mh = 0; mh < 2; ++mh) {
            f32x4 vR = mh ? aR1 : aR0;
            f32x4 vZ = mh ? aZ1 : aZ0;
            f32x4 vN = mh ? aN1 : aN0;
            #pragma unroll
            for (int v = 0; v < 4; ++v) {
                int irow = tile * MTILE + (2 * w + mh) * 16 + lhi * 4 + v;
                if (irow >= count) continue;
                size_t pos = (size_t)(base + irow);
                int off = prevoff[pos];
                const unsigned short* hp_ptr = (off >= 0) ? (hperm + off)
                    : (off == -1 ? zeropage : (h0bf + (-off - 2)));
                int col = slice * 16 + l15;
                float hp = b2f(hp_ptr[col]);
                const unsigned short* gp = gxp + pos * 1536 + col;
                float gr = b2f(gp[0]);
                float gz = b2f(gp[512]);
                float gn = b2f(gp[1024]);
                float r = 1.f / (1.f + __expf(-(gr + vR[v])));
                float z = 1.f / (1.f + __expf(-(gz + vZ[v])));
                float nn = tanhf(gn + r * vN[v]);
                hperm[pos * 512 + col] = (unsigned short)f2b((1.f - z) * nn + z * hp);
            }
        }
    }
}

// ---------------------------------------------------------------------------
// hlast: h[n, L-1, :] -> fp32 ws (via pos_of; before hexp overwrites hperm)
// ---------------------------------------------------------------------------
__global__ __launch_bounds__(256) void hlast_kernel(
    const unsigned short* __restrict__ hperm, const int* __restrict__ pos_of,
    float* __restrict__ hlast)
{
    int i = blockIdx.x * 256 + threadIdx.x;
    if (i >= NB * HD) return;
    int n = i >> 9, c = i & 511;
    size_t pos = (size_t)pos_of[n * LSEQ + (LSEQ - 1)];
    hlast[i] = b2f(hperm[pos * HD + c]);
}

// ---------------------------------------------------------------------------
// LayerNorm: out1[n,l] = LN(hperm[pos_of[n,l]] + inp[n,l]) * gamma + beta
// ---------------------------------------------------------------------------
__global__ __launch_bounds__(256) void ln_kernel(
    const unsigned short* __restrict__ hperm, const int* __restrict__ pos_of,
    const float* __restrict__ inp,
    const float* __restrict__ gamma, const float* __restrict__ beta,
    float* __restrict__ out1)
{
    size_t row = blockIdx.x;
    int tid = threadIdx.x;
    int c = tid * 2;
    size_t pos = (size_t)pos_of[row];
    const unsigned short* yrow = hperm + pos * HD;
    const float* xrow = inp + row * HD;
    ushort2 yv = *(const ushort2*)(yrow + c);
    float2 xv = *(const float2*)(xrow + c);
    float a = b2f(yv.x) + xv.x;
    float b = b2f(yv.y) + xv.y;
    float s = a + b, ss = a * a + b * b;
    #pragma unroll
    for (int m = 1; m < 64; m <<= 1) {
        s  += __shfl_xor(s, m, 64);
        ss += __shfl_xor(ss, m, 64);
    }
    __shared__ float ps[4], pss[4];
    int w = tid >> 6;
    if ((tid & 63) == 0) { ps[w] = s; pss[w] = ss; }
    __syncthreads();
    s  = ps[0] + ps[1] + ps[2] + ps[3];
    ss = pss[0] + pss[1] + pss[2] + pss[3];
    float mu = s * (1.f / 512.f);
    float var = ss * (1.f / 512.f) - mu * mu;
    float inv = rsqrtf(var + 1e-5f);
    float2 gv = *(const float2*)(gamma + c);
    float2 bv = *(const float2*)(beta + c);
    float2 o;
    o.x = (a - mu) * inv * gv.x + bv.x;
    o.y = (b - mu) * inv * gv.y + bv.y;
    *(float2*)(out1 + row * HD + c) = o;
}

// ---------------------------------------------------------------------------
// hexp: out2[n,l,:] = hlast[n,:]  (overwrites gxp tail + hperm; runs last)
// ---------------------------------------------------------------------------
__global__ __launch_bounds__(256) void hexp_kernel(
    const float* __restrict__ hlast, float* __restrict__ out2)
{
    size_t idx = (size_t)blockIdx.x * 256 + threadIdx.x;   // float4 units
    if (idx >= (size_t)NI * HD / 4) return;
    int per_n = LSEQ * HD / 4;
    int n = (int)(idx / per_n);
    int c4 = (int)(idx & (HD / 4 - 1));
    float4 v = *(const float4*)(hlast + n * HD + c4 * 4);
    *(float4*)(out2 + idx * 4) = v;
}

// ---------------------------------------------------------------------------
extern "C" void kernel_launch(void* const* d_in, const int* in_sizes, int n_in,
                              void* d_out, int out_size, void* d_ws, size_t ws_size,
                              hipStream_t stream)
{
    const float* inp   = (const float*)d_in[0];
    const float* h0    = (const float*)d_in[1];
    const int*  is_ini = (const int*)d_in[2];
    const float* W_ih  = (const float*)d_in[3];
    const float* W_hh  = (const float*)d_in[4];
    const float* b_ih  = (const float*)d_in[5];
    const float* b_hh  = (const float*)d_in[6];
    const float* gamma = (const float*)d_in[7];
    const float* beta  = (const float*)d_in[8];

    const size_t NLH = (size_t)NI * HD;            // 33,554,432
    float* out1 = (float*)d_out;
    float* out2 = out1 + NLH;
    // d_out overlay (268.4 MB):
    //   gxp   bf16 [NI][1536] = 201.3 MB at offset 0      (dead after phases)
    //   hperm bf16 [NI][512]  =  67.1 MB at offset 201.3  (dead after hlast/ln)
    unsigned short* gxp   = (unsigned short*)d_out;
    unsigned short* hperm = gxp + (size_t)NI * 1536;

    unsigned short* Xpack = (unsigned short*)d_ws;            // 1.5 MB
    unsigned short* Hpack = Xpack + 1536 * 512;               // 1.5 MB
    int* counts  = (int*)(Hpack + 1536 * 512);                // 2 KB
    int* offsets = counts + LSEQ;                             // 2 KB
    unsigned* items = (unsigned*)(offsets + LSEQ);            // 256 KB
    int* pos_of  = (int*)(items + NI);                        // 256 KB
    int* prevoff = pos_of + NI;                               // 256 KB
    unsigned short* h0bf = (unsigned short*)(prevoff + NI);   // 128 KB
    unsigned short* zeropage = h0bf + NB * HD;                // 2 KB
    float* hlast = (float*)(zeropage + 1024);                 // 256 KB

    setup_kernel<<<(NB * HD + 255) / 256, 256, 0, stream>>>(h0, h0bf, zeropage);
    pack_kernel<<<(1536 * 512 + 255) / 256, 256, 0, stream>>>(W_ih, W_hh, Xpack, Hpack);
    sched_kernel<<<1, 128, 0, stream>>>(is_ini, counts, offsets, items, pos_of, prevoff);

    gxp_kernel<<<dim3(NI / 32, 2), 512, 0, stream>>>(inp, Xpack, b_ih, items, gxp);

    for (int d = 0; d < MAX_DEPTH; d++) {
        wphase_kernel<<<SLICES * GRPS, 512, 0, stream>>>(
            d, Hpack, b_hh, counts, offsets, prevoff,
            gxp, h0bf, zeropage, hperm);
    }

    hlast_kernel<<<(NB * HD + 255) / 256, 256, 0, stream>>>(hperm, pos_of, hlast);
    ln_kernel<<<NI, 256, 0, stream>>>(hperm, pos_of, inp, gamma, beta, out1);
    hexp_kernel<<<(int)(NLH / 4 / 256), 256, 0, stream>>>(hlast, out2);
}